// Round 11
// baseline (93.610 us; speedup 1.0000x reference)
//
#include <hip/hip_runtime.h>
#include <math.h>

// DiscriminativeLoss: N=1e6 x D=32 fp32, K=64, scalar out.
// R11 = R8 base (65.8us, best) + ONE change: reduce1+mean merged into
// means_kernel (65 blocks; block k reduces cluster k's 32 dims over all 977
// partials, 8-way y-split + LDS tree; block 64 -> icnt). R10's NPTS=2048
// reverted (489 blocks = 1.9/CU under-subscription, +7.5us).
// Lessons: no volume/same-line global atomics (R5/R6); per-cluster register
// walk (R6); NPTS=1024 is the pass1 occupancy/divergence optimum (R7/R10);
// one variable per round (R9/R10).

#define EPS_F 1e-8f
constexpr int D = 32;
constexpr int K = 64;
constexpr int NPTS = 1024;               // points per pass1 block
constexpr int P1 = K * D + K;            // 2112: 2048 sums + 64 counts
constexpr int NBLK2 = 2048;              // pass2 blocks
constexpr int MPAD = 40;                 // LDS means row stride

// ---------------- pass 1: sort-by-label, register segment sums -------------
__global__ __launch_bounds__(256, 4) void pass1_kernel(
    const float* __restrict__ feat, const int* __restrict__ lab,
    float* __restrict__ part1, int N)
{
    __shared__ int            s_lab[NPTS];
    __shared__ unsigned short s_idx[NPTS];
    __shared__ int            s_hist[K];
    __shared__ int            s_pref[K];
    __shared__ int            s_cur[K];

    const int tid = threadIdx.x;
    const long long base = (long long)blockIdx.x * NPTS;
    int npts = (int)((long long)N - base);
    if (npts > NPTS) npts = NPTS;

    if (tid < K) s_hist[tid] = 0;
    __syncthreads();

    // stage labels (coalesced int4) + histogram (1 int atomic per point)
    const int n4 = npts >> 2;
    for (int i4 = tid; i4 < n4; i4 += 256) {
        const int4 v = ((const int4*)(lab + base))[i4];
        s_lab[i4 * 4 + 0] = v.x; s_lab[i4 * 4 + 1] = v.y;
        s_lab[i4 * 4 + 2] = v.z; s_lab[i4 * 4 + 3] = v.w;
        atomicAdd(&s_hist[v.x], 1); atomicAdd(&s_hist[v.y], 1);
        atomicAdd(&s_hist[v.z], 1); atomicAdd(&s_hist[v.w], 1);
    }
    for (int i = (n4 << 2) + tid; i < npts; i += 256) {  // tail
        const int l = lab[base + i];
        s_lab[i] = l;
        atomicAdd(&s_hist[l], 1);
    }
    __syncthreads();

    // exclusive prefix over 64 bins (wave 0)
    if (tid < 64) {
        const int h = s_hist[tid];
        int v = h;
        for (int off = 1; off < 64; off <<= 1) {
            const int up = __shfl_up(v, off);
            if (tid >= off) v += up;
        }
        s_pref[tid] = v - h;
        s_cur[tid]  = v - h;
    }
    __syncthreads();

    // scatter sorted indices (1 int atomic per point)
    for (int i = tid; i < npts; i += 256) {
        const int l = s_lab[i];
        const int pos = atomicAdd(&s_cur[l], 1);
        s_idx[pos] = (unsigned short)i;
    }
    __syncthreads();

    // register accumulation: thread owns cluster k = tid>>2, dims q*8..q*8+7
    const int k = tid >> 2, q = tid & 3;
    const int start = s_pref[k], len = s_hist[k];
    float4 a0 = {0.f, 0.f, 0.f, 0.f}, a1 = {0.f, 0.f, 0.f, 0.f};
    int i = 0;
    for (; i + 4 <= len; i += 4) {            // unroll x4: 8 loads in flight
        const int i0 = s_idx[start + i + 0];
        const int i1 = s_idx[start + i + 1];
        const int i2 = s_idx[start + i + 2];
        const int i3 = s_idx[start + i + 3];
        const float4* r0 = (const float4*)(feat + (base + i0) * D + q * 8);
        const float4* r1 = (const float4*)(feat + (base + i1) * D + q * 8);
        const float4* r2 = (const float4*)(feat + (base + i2) * D + q * 8);
        const float4* r3 = (const float4*)(feat + (base + i3) * D + q * 8);
        const float4 x0 = r0[0], y0 = r0[1];
        const float4 x1 = r1[0], y1 = r1[1];
        const float4 x2 = r2[0], y2 = r2[1];
        const float4 x3 = r3[0], y3 = r3[1];
        a0.x += (x0.x + x1.x) + (x2.x + x3.x);
        a0.y += (x0.y + x1.y) + (x2.y + x3.y);
        a0.z += (x0.z + x1.z) + (x2.z + x3.z);
        a0.w += (x0.w + x1.w) + (x2.w + x3.w);
        a1.x += (y0.x + y1.x) + (y2.x + y3.x);
        a1.y += (y0.y + y1.y) + (y2.y + y3.y);
        a1.z += (y0.z + y1.z) + (y2.z + y3.z);
        a1.w += (y0.w + y1.w) + (y2.w + y3.w);
    }
    for (; i < len; ++i) {
        const int i0 = s_idx[start + i];
        const float4* r0 = (const float4*)(feat + (base + i0) * D + q * 8);
        const float4 x0 = r0[0], y0 = r0[1];
        a0.x += x0.x; a0.y += x0.y; a0.z += x0.z; a0.w += x0.w;
        a1.x += y0.x; a1.y += y0.y; a1.z += y0.z; a1.w += y0.w;
    }
    float* outp = part1 + (long long)blockIdx.x * P1;
    ((float4*)outp)[tid * 2 + 0] = a0;        // cell k*32 + q*8 == tid*8
    ((float4*)outp)[tid * 2 + 1] = a1;
    if (tid < K) outp[K * D + tid] = (float)s_hist[tid];
}

// ---------------- means: all partials -> means, icnt (one kernel) ----------
// blocks 0..K-1: block k reduces cluster k's 32 dims (+its count) over all
// nblk1 partials with 8-way y-split; block K: counts -> icnt.
__global__ __launch_bounds__(256) void means_kernel(
    const float* __restrict__ part1, int nblk1,
    float* __restrict__ means, float* __restrict__ icnt)
{
    __shared__ float s_s[256];
    __shared__ float s_c[256];
    const int tid = threadIdx.x;
    const int bid = blockIdx.x;
    if (bid < K) {
        const int el = tid & 31, y = tid >> 5;       // 8 y-groups x 32 dims
        float s = 0.f, c = 0.f;
        for (int b = y; b < nblk1; b += 8) {
            const float* pb = part1 + (long long)b * P1;
            s += pb[bid * 32 + el];                  // coalesced 128B/y-group
            c += pb[K * D + bid];                    // broadcast within group
        }
        s_s[tid] = s; s_c[tid] = c;
        __syncthreads();
        for (int off = 128; off >= 32; off >>= 1) {
            if (tid < off) { s_s[tid] += s_s[tid + off]; s_c[tid] += s_c[tid + off]; }
            __syncthreads();
        }
        if (tid < 32) means[bid * 32 + tid] = s_s[tid] / fmaxf(s_c[tid], 1.0f);
    } else {
        const int el = tid & 63, y = tid >> 6;       // 4 y-groups x 64 counts
        float c = 0.f;
        for (int b = y; b < nblk1; b += 4)
            c += part1[(long long)b * P1 + K * D + el];
        s_c[tid] = c;
        __syncthreads();
        if (tid < 128) s_c[tid] += s_c[tid + 128];
        __syncthreads();
        if (tid < 64) icnt[tid] = 1.0f / fmaxf(s_c[tid] + s_c[tid + 64], 1.0f);
    }
}

// ---------------- pass 2: lane-owns-point hinge + block0 inter/reg ---------
__global__ __launch_bounds__(256, 4) void pass2_kernel(
    const float* __restrict__ feat, const int* __restrict__ lab,
    const float* __restrict__ means, const float* __restrict__ icnt,
    float* __restrict__ hpart, float* __restrict__ ir, int N)
{
    __shared__ float s_m[K * MPAD];   // padded means, 10 KB
    __shared__ float s_ic[K];
    __shared__ float s_red[256];
    const int tid = threadIdx.x;

    for (int e = tid; e < K * D; e += 256)
        s_m[(e >> 5) * MPAD + (e & 31)] = means[e];
    if (tid < K) s_ic[tid] = icnt[tid];
    __syncthreads();

    float racc = 0.f;
    const long long stride = (long long)NBLK2 * 256;
    for (long long p = (long long)blockIdx.x * 256 + tid; p < N; p += stride) {
        const int l = lab[p];
        const float4* frow = (const float4*)(feat + p * D);
        float4 fv[8];
        #pragma unroll
        for (int j = 0; j < 8; j++) fv[j] = frow[j];   // 8 loads in flight
        const float* mrow = s_m + l * MPAD;
        float d2 = 0.f;
        #pragma unroll
        for (int j = 0; j < 8; j++) {
            const float4 mv = *(const float4*)(mrow + j * 4);
            const float dx = fv[j].x - mv.x + EPS_F;
            const float dy = fv[j].y - mv.y + EPS_F;
            const float dz = fv[j].z - mv.z + EPS_F;
            const float dw = fv[j].w - mv.w + EPS_F;
            d2 += dx * dx + dy * dy + dz * dz + dw * dw;
        }
        const float h = fmaxf(sqrtf(d2) - 1.5f, 0.f);  // INTRA_MARGIN_USED
        racc += h * h * s_ic[l];
    }
    s_red[tid] = racc;
    __syncthreads();
    for (int st = 128; st; st >>= 1) { if (tid < st) s_red[tid] += s_red[tid + st]; __syncthreads(); }
    if (tid == 0) hpart[blockIdx.x] = s_red[0];

    if (blockIdx.x != 0) return;
    // ---- block 0 epilogue: inter + reg from s_m (overlaps other blocks) ----
    __syncthreads();
    float mj[32];
    const int j = tid & 63;
    #pragma unroll
    for (int d = 0; d < 32; d++) mj[d] = s_m[j * MPAD + d];
    float isum = 0.f;
    const int igrp = tid >> 6;        // 0..3, 16 i's each; i wave-uniform
    for (int ii = 0; ii < 16; ii++) {
        const int i = igrp * 16 + ii;
        const float4* srow = (const float4*)(s_m + i * MPAD);
        float d2 = 0.f;
        #pragma unroll
        for (int q = 0; q < 8; q++) {
            const float4 mv = srow[q];
            const float b0 = mv.x - mj[q * 4 + 0] + EPS_F;
            const float b1 = mv.y - mj[q * 4 + 1] + EPS_F;
            const float b2 = mv.z - mj[q * 4 + 2] + EPS_F;
            const float b3 = mv.w - mj[q * 4 + 3] + EPS_F;
            d2 += b0 * b0 + b1 * b1 + b2 * b2 + b3 * b3;
        }
        if (i != j) {
            const float h = fmaxf(1.0f - sqrtf(d2), 0.f);  // 2*margin - pd
            isum += h * h;
        }
    }
    s_red[tid] = isum;
    __syncthreads();
    for (int st = 128; st; st >>= 1) { if (tid < st) s_red[tid] += s_red[tid + st]; __syncthreads(); }
    if (tid == 0) ir[0] = s_red[0] * (1.0f / ((K - 1) * K));
    __syncthreads();

    float r = 0.f;
    if (tid < 64) {
        float d2 = 0.f;
        #pragma unroll
        for (int d = 0; d < 32; d++) { const float t = mj[d] + EPS_F; d2 += t * t; }
        r = sqrtf(d2);
    }
    s_red[tid] = r;
    __syncthreads();
    for (int st = 128; st; st >>= 1) { if (tid < st) s_red[tid] += s_red[tid + st]; __syncthreads(); }
    if (tid == 0) ir[1] = s_red[0] * (1.0f / K);
}

// ---------------- final: hpart sum + combine --------------------------------
__global__ __launch_bounds__(256) void final_kernel(
    const float* __restrict__ hpart, const float* __restrict__ ir,
    float* __restrict__ out)
{
    __shared__ float s_red[256];
    const int tid = threadIdx.x;
    float hs = 0.f;
    for (int b = tid; b < NBLK2; b += 256) hs += hpart[b];
    s_red[tid] = hs;
    __syncthreads();
    for (int st = 128; st; st >>= 1) { if (tid < st) s_red[tid] += s_red[tid + st]; __syncthreads(); }
    if (tid == 0) out[0] = s_red[0] * (1.0f / K) + ir[0] + 0.001f * ir[1];
}

extern "C" void kernel_launch(void* const* d_in, const int* in_sizes, int n_in,
                              void* d_out, int out_size, void* d_ws, size_t ws_size,
                              hipStream_t stream)
{
    const float* feat = (const float*)d_in[0];
    const int*   lab  = (const int*)d_in[1];
    const int N = in_sizes[1];            // 1e6; D=32, K=64 fixed by reference

    float* ws = (float*)d_ws;

    const int nblk1 = (N + NPTS - 1) / NPTS;         // 977

    float* means = ws;                               // K*D
    float* icnt  = means + K * D;                    // K
    float* ir    = icnt + K;                         // 2 (+pad 2)
    float* hpart = ir + 4;                           // NBLK2
    float* part1 = hpart + NBLK2;                    // nblk1*P1

    pass1_kernel<<<nblk1, 256, 0, stream>>>(feat, lab, part1, N);
    means_kernel<<<K + 1, 256, 0, stream>>>(part1, nblk1, means, icnt);
    pass2_kernel<<<NBLK2, 256, 0, stream>>>(feat, lab, means, icnt, hpart, ir, N);
    final_kernel<<<1, 256, 0, stream>>>(hpart, ir, (float*)d_out);
}

// Round 12
// 65.777 us; speedup vs baseline: 1.4232x; 1.4232x over previous
//
#include <hip/hip_runtime.h>
#include <math.h>

// DiscriminativeLoss: N=1e6 x D=32 fp32, K=64, scalar out.
// R12 = R8 verbatim (65.8us, confirmed best) + ONE change: mean_kernel
// parallelized (33 blocks x 4 y-groups, serial chunk loop 64->16, LDS
// combine). R11's 65-block means-merge reverted (+28us: 0.25 blk/CU,
// line-sparse reads -> latency-bound; same disease as R1).
// Lessons: merges only win if merged geometry keeps grid saturated
// (R1/R10/R11); no volume/same-line global atomics (R5/R6); per-cluster
// register walk (R6); NPTS=1024 optimum (R7/R10); one variable per round.

#define EPS_F 1e-8f
constexpr int D = 32;
constexpr int K = 64;
constexpr int NPTS = 1024;               // points per pass1 block
constexpr int P1 = K * D + K;            // 2112: 2048 sums + 64 counts
constexpr int NCH = 64;                  // reduction chunks
constexpr int NBLK2 = 2048;              // pass2 blocks
constexpr int MPAD = 40;                 // LDS means row stride

// ---------------- pass 1: sort-by-label, register segment sums -------------
__global__ __launch_bounds__(256, 4) void pass1_kernel(
    const float* __restrict__ feat, const int* __restrict__ lab,
    float* __restrict__ part1, int N)
{
    __shared__ int            s_lab[NPTS];
    __shared__ unsigned short s_idx[NPTS];
    __shared__ int            s_hist[K];
    __shared__ int            s_pref[K];
    __shared__ int            s_cur[K];

    const int tid = threadIdx.x;
    const long long base = (long long)blockIdx.x * NPTS;
    int npts = (int)((long long)N - base);
    if (npts > NPTS) npts = NPTS;

    if (tid < K) s_hist[tid] = 0;
    __syncthreads();

    // stage labels (coalesced int4) + histogram (1 int atomic per point)
    const int n4 = npts >> 2;
    for (int i4 = tid; i4 < n4; i4 += 256) {
        const int4 v = ((const int4*)(lab + base))[i4];
        s_lab[i4 * 4 + 0] = v.x; s_lab[i4 * 4 + 1] = v.y;
        s_lab[i4 * 4 + 2] = v.z; s_lab[i4 * 4 + 3] = v.w;
        atomicAdd(&s_hist[v.x], 1); atomicAdd(&s_hist[v.y], 1);
        atomicAdd(&s_hist[v.z], 1); atomicAdd(&s_hist[v.w], 1);
    }
    for (int i = (n4 << 2) + tid; i < npts; i += 256) {  // tail
        const int l = lab[base + i];
        s_lab[i] = l;
        atomicAdd(&s_hist[l], 1);
    }
    __syncthreads();

    // exclusive prefix over 64 bins (wave 0)
    if (tid < 64) {
        const int h = s_hist[tid];
        int v = h;
        for (int off = 1; off < 64; off <<= 1) {
            const int up = __shfl_up(v, off);
            if (tid >= off) v += up;
        }
        s_pref[tid] = v - h;
        s_cur[tid]  = v - h;
    }
    __syncthreads();

    // scatter sorted indices (1 int atomic per point)
    for (int i = tid; i < npts; i += 256) {
        const int l = s_lab[i];
        const int pos = atomicAdd(&s_cur[l], 1);
        s_idx[pos] = (unsigned short)i;
    }
    __syncthreads();

    // register accumulation: thread owns cluster k = tid>>2, dims q*8..q*8+7
    const int k = tid >> 2, q = tid & 3;
    const int start = s_pref[k], len = s_hist[k];
    float4 a0 = {0.f, 0.f, 0.f, 0.f}, a1 = {0.f, 0.f, 0.f, 0.f};
    int i = 0;
    for (; i + 4 <= len; i += 4) {            // unroll x4: 8 loads in flight
        const int i0 = s_idx[start + i + 0];
        const int i1 = s_idx[start + i + 1];
        const int i2 = s_idx[start + i + 2];
        const int i3 = s_idx[start + i + 3];
        const float4* r0 = (const float4*)(feat + (base + i0) * D + q * 8);
        const float4* r1 = (const float4*)(feat + (base + i1) * D + q * 8);
        const float4* r2 = (const float4*)(feat + (base + i2) * D + q * 8);
        const float4* r3 = (const float4*)(feat + (base + i3) * D + q * 8);
        const float4 x0 = r0[0], y0 = r0[1];
        const float4 x1 = r1[0], y1 = r1[1];
        const float4 x2 = r2[0], y2 = r2[1];
        const float4 x3 = r3[0], y3 = r3[1];
        a0.x += (x0.x + x1.x) + (x2.x + x3.x);
        a0.y += (x0.y + x1.y) + (x2.y + x3.y);
        a0.z += (x0.z + x1.z) + (x2.z + x3.z);
        a0.w += (x0.w + x1.w) + (x2.w + x3.w);
        a1.x += (y0.x + y1.x) + (y2.x + y3.x);
        a1.y += (y0.y + y1.y) + (y2.y + y3.y);
        a1.z += (y0.z + y1.z) + (y2.z + y3.z);
        a1.w += (y0.w + y1.w) + (y2.w + y3.w);
    }
    for (; i < len; ++i) {
        const int i0 = s_idx[start + i];
        const float4* r0 = (const float4*)(feat + (base + i0) * D + q * 8);
        const float4 x0 = r0[0], y0 = r0[1];
        a0.x += x0.x; a0.y += x0.y; a0.z += x0.z; a0.w += x0.w;
        a1.x += y0.x; a1.y += y0.y; a1.z += y0.z; a1.w += y0.w;
    }
    float* outp = part1 + (long long)blockIdx.x * P1;
    ((float4*)outp)[tid * 2 + 0] = a0;        // cell k*32 + q*8 == tid*8
    ((float4*)outp)[tid * 2 + 1] = a1;
    if (tid < K) outp[K * D + tid] = (float)s_hist[tid];
}

// ---------------- stage A: nblk1 partials -> NCH partials (coalesced) ------
__global__ __launch_bounds__(256) void reduce1_kernel(
    const float* __restrict__ part1, float* __restrict__ part2,
    int chsz, int nblk1)
{
    const int e = blockIdx.x * 256 + threadIdx.x;
    if (e >= P1) return;
    const int y = blockIdx.y;
    const int b0 = y * chsz;
    int b1 = b0 + chsz; if (b1 > nblk1) b1 = nblk1;
    float s = 0.f;
    for (int b = b0; b < b1; b++) s += part1[(long long)b * P1 + e];
    part2[(long long)y * P1 + e] = s;
}

// ---------------- stage B: NCH partials -> means, inv_counts (y-split x4) --
__global__ __launch_bounds__(256) void mean_kernel(
    const float* __restrict__ part2,
    float* __restrict__ means, float* __restrict__ icnt)
{
    __shared__ float s_s[256];
    __shared__ float s_c[256];
    const int tid = threadIdx.x;
    const int el  = blockIdx.x * 64 + (tid & 63);    // element in [0, P1)
    const int y   = tid >> 6;                        // 0..3
    float s = 0.f, c = 0.f;
    if (el < P1) {
        const int kcol = K * D + (el >> 5);          // count slot for el<K*D
        for (int ych = y; ych < NCH; ych += 4) {     // 16 iters (was 64)
            const float* pb = part2 + (long long)ych * P1;
            s += pb[el];                             // coalesced 256B/group
            if (el < K * D) c += pb[kcol];           // broadcast line
        }
    }
    s_s[tid] = s; s_c[tid] = c;
    __syncthreads();
    if (tid < 64) {
        const float ss = s_s[tid] + s_s[tid + 64] + s_s[tid + 128] + s_s[tid + 192];
        const float cc = s_c[tid] + s_c[tid + 64] + s_c[tid + 128] + s_c[tid + 192];
        const int e = blockIdx.x * 64 + tid;
        if (e < K * D)      means[e] = ss / fmaxf(cc, 1.0f);
        else if (e < P1)    icnt[e - K * D] = 1.0f / fmaxf(ss, 1.0f);
    }
}

// ---------------- pass 2: lane-owns-point hinge + block0 inter/reg ---------
__global__ __launch_bounds__(256, 4) void pass2_kernel(
    const float* __restrict__ feat, const int* __restrict__ lab,
    const float* __restrict__ means, const float* __restrict__ icnt,
    float* __restrict__ hpart, float* __restrict__ ir, int N)
{
    __shared__ float s_m[K * MPAD];   // padded means, 10 KB
    __shared__ float s_ic[K];
    __shared__ float s_red[256];
    const int tid = threadIdx.x;

    for (int e = tid; e < K * D; e += 256)
        s_m[(e >> 5) * MPAD + (e & 31)] = means[e];
    if (tid < K) s_ic[tid] = icnt[tid];
    __syncthreads();

    float racc = 0.f;
    const long long stride = (long long)NBLK2 * 256;
    for (long long p = (long long)blockIdx.x * 256 + tid; p < N; p += stride) {
        const int l = lab[p];
        const float4* frow = (const float4*)(feat + p * D);
        float4 fv[8];
        #pragma unroll
        for (int j = 0; j < 8; j++) fv[j] = frow[j];   // 8 loads in flight
        const float* mrow = s_m + l * MPAD;
        float d2 = 0.f;
        #pragma unroll
        for (int j = 0; j < 8; j++) {
            const float4 mv = *(const float4*)(mrow + j * 4);
            const float dx = fv[j].x - mv.x + EPS_F;
            const float dy = fv[j].y - mv.y + EPS_F;
            const float dz = fv[j].z - mv.z + EPS_F;
            const float dw = fv[j].w - mv.w + EPS_F;
            d2 += dx * dx + dy * dy + dz * dz + dw * dw;
        }
        const float h = fmaxf(sqrtf(d2) - 1.5f, 0.f);  // INTRA_MARGIN_USED
        racc += h * h * s_ic[l];
    }
    s_red[tid] = racc;
    __syncthreads();
    for (int st = 128; st; st >>= 1) { if (tid < st) s_red[tid] += s_red[tid + st]; __syncthreads(); }
    if (tid == 0) hpart[blockIdx.x] = s_red[0];

    if (blockIdx.x != 0) return;
    // ---- block 0 epilogue: inter + reg from s_m (overlaps other blocks) ----
    __syncthreads();
    float mj[32];
    const int j = tid & 63;
    #pragma unroll
    for (int d = 0; d < 32; d++) mj[d] = s_m[j * MPAD + d];
    float isum = 0.f;
    const int igrp = tid >> 6;        // 0..3, 16 i's each; i wave-uniform
    for (int ii = 0; ii < 16; ii++) {
        const int i = igrp * 16 + ii;
        const float4* srow = (const float4*)(s_m + i * MPAD);
        float d2 = 0.f;
        #pragma unroll
        for (int q = 0; q < 8; q++) {
            const float4 mv = srow[q];
            const float b0 = mv.x - mj[q * 4 + 0] + EPS_F;
            const float b1 = mv.y - mj[q * 4 + 1] + EPS_F;
            const float b2 = mv.z - mj[q * 4 + 2] + EPS_F;
            const float b3 = mv.w - mj[q * 4 + 3] + EPS_F;
            d2 += b0 * b0 + b1 * b1 + b2 * b2 + b3 * b3;
        }
        if (i != j) {
            const float h = fmaxf(1.0f - sqrtf(d2), 0.f);  // 2*margin - pd
            isum += h * h;
        }
    }
    s_red[tid] = isum;
    __syncthreads();
    for (int st = 128; st; st >>= 1) { if (tid < st) s_red[tid] += s_red[tid + st]; __syncthreads(); }
    if (tid == 0) ir[0] = s_red[0] * (1.0f / ((K - 1) * K));
    __syncthreads();

    float r = 0.f;
    if (tid < 64) {
        float d2 = 0.f;
        #pragma unroll
        for (int d = 0; d < 32; d++) { const float t = mj[d] + EPS_F; d2 += t * t; }
        r = sqrtf(d2);
    }
    s_red[tid] = r;
    __syncthreads();
    for (int st = 128; st; st >>= 1) { if (tid < st) s_red[tid] += s_red[tid + st]; __syncthreads(); }
    if (tid == 0) ir[1] = s_red[0] * (1.0f / K);
}

// ---------------- final: hpart sum + combine --------------------------------
__global__ __launch_bounds__(256) void final_kernel(
    const float* __restrict__ hpart, const float* __restrict__ ir,
    float* __restrict__ out)
{
    __shared__ float s_red[256];
    const int tid = threadIdx.x;
    float hs = 0.f;
    for (int b = tid; b < NBLK2; b += 256) hs += hpart[b];
    s_red[tid] = hs;
    __syncthreads();
    for (int st = 128; st; st >>= 1) { if (tid < st) s_red[tid] += s_red[tid + st]; __syncthreads(); }
    if (tid == 0) out[0] = s_red[0] * (1.0f / K) + ir[0] + 0.001f * ir[1];
}

extern "C" void kernel_launch(void* const* d_in, const int* in_sizes, int n_in,
                              void* d_out, int out_size, void* d_ws, size_t ws_size,
                              hipStream_t stream)
{
    const float* feat = (const float*)d_in[0];
    const int*   lab  = (const int*)d_in[1];
    const int N = in_sizes[1];            // 1e6; D=32, K=64 fixed by reference

    float* ws = (float*)d_ws;

    const int nblk1 = (N + NPTS - 1) / NPTS;         // 977
    const int chsz  = (nblk1 + NCH - 1) / NCH;       // 16

    float* means = ws;                               // K*D
    float* icnt  = means + K * D;                    // K
    float* ir    = icnt + K;                         // 2 (+pad 2)
    float* part2 = ir + 4;                           // NCH*P1
    float* hpart = part2 + (long long)NCH * P1;      // NBLK2
    float* part1 = hpart + NBLK2;                    // nblk1*P1

    pass1_kernel<<<nblk1, 256, 0, stream>>>(feat, lab, part1, N);
    reduce1_kernel<<<dim3((P1 + 255) / 256, NCH), 256, 0, stream>>>(part1, part2, chsz, nblk1);
    mean_kernel<<<(P1 + 63) / 64, 256, 0, stream>>>(part2, means, icnt);
    pass2_kernel<<<NBLK2, 256, 0, stream>>>(feat, lab, means, icnt, hpart, ir, N);
    final_kernel<<<1, 256, 0, stream>>>(hpart, ir, (float*)d_out);
}

// Round 13
// 62.024 us; speedup vs baseline: 1.5093x; 1.0605x over previous
//
#include <hip/hip_runtime.h>
#include <math.h>

// DiscriminativeLoss: N=1e6 x D=32 fp32, K=64, scalar out.
// R13 = R12 base (65.8us) with dispatch-count reduction, all geometries kept:
// - mean_kernel deleted; reduce1 -> reduce1_atomic (same 577-block coalesced
//   reads, fire-and-forget atomicAdd of chunk-partials into global sums/cnt:
//   135K non-returning atomics, 64 contenders/addr — 1.7% of R5's volume).
// - pass1 block 0 zeroes sums/cnt (stream order guarantees before reduce1).
// - pass2 prologue computes means = sums/max(cnt,1) while staging LDS.
// 5 kernels -> 4. Lessons: merges must keep grid saturated (R1/R10/R11);
// no returning-atomic tails (R6); no per-thread-volume atomics (R5);
// NPTS=1024 optimum (R7/R10).

#define EPS_F 1e-8f
constexpr int D = 32;
constexpr int K = 64;
constexpr int NPTS = 1024;               // points per pass1 block
constexpr int P1 = K * D + K;            // 2112: 2048 sums + 64 counts
constexpr int NCH = 64;                  // reduction chunks
constexpr int NBLK2 = 2048;              // pass2 blocks
constexpr int MPAD = 40;                 // LDS means row stride

// ---------------- pass 1: sort-by-label, register segment sums -------------
__global__ __launch_bounds__(256, 4) void pass1_kernel(
    const float* __restrict__ feat, const int* __restrict__ lab,
    float* __restrict__ part1, float* __restrict__ sums, int N)
{
    __shared__ int            s_lab[NPTS];
    __shared__ unsigned short s_idx[NPTS];
    __shared__ int            s_hist[K];
    __shared__ int            s_pref[K];
    __shared__ int            s_cur[K];

    const int tid = threadIdx.x;
    const long long base = (long long)blockIdx.x * NPTS;
    int npts = (int)((long long)N - base);
    if (npts > NPTS) npts = NPTS;

    if (blockIdx.x == 0)                       // zero global accumulator
        for (int e = tid; e < P1; e += 256) sums[e] = 0.f;

    if (tid < K) s_hist[tid] = 0;
    __syncthreads();

    // stage labels (coalesced int4) + histogram (1 int atomic per point)
    const int n4 = npts >> 2;
    for (int i4 = tid; i4 < n4; i4 += 256) {
        const int4 v = ((const int4*)(lab + base))[i4];
        s_lab[i4 * 4 + 0] = v.x; s_lab[i4 * 4 + 1] = v.y;
        s_lab[i4 * 4 + 2] = v.z; s_lab[i4 * 4 + 3] = v.w;
        atomicAdd(&s_hist[v.x], 1); atomicAdd(&s_hist[v.y], 1);
        atomicAdd(&s_hist[v.z], 1); atomicAdd(&s_hist[v.w], 1);
    }
    for (int i = (n4 << 2) + tid; i < npts; i += 256) {  // tail
        const int l = lab[base + i];
        s_lab[i] = l;
        atomicAdd(&s_hist[l], 1);
    }
    __syncthreads();

    // exclusive prefix over 64 bins (wave 0)
    if (tid < 64) {
        const int h = s_hist[tid];
        int v = h;
        for (int off = 1; off < 64; off <<= 1) {
            const int up = __shfl_up(v, off);
            if (tid >= off) v += up;
        }
        s_pref[tid] = v - h;
        s_cur[tid]  = v - h;
    }
    __syncthreads();

    // scatter sorted indices (1 int atomic per point)
    for (int i = tid; i < npts; i += 256) {
        const int l = s_lab[i];
        const int pos = atomicAdd(&s_cur[l], 1);
        s_idx[pos] = (unsigned short)i;
    }
    __syncthreads();

    // register accumulation: thread owns cluster k = tid>>2, dims q*8..q*8+7
    const int k = tid >> 2, q = tid & 3;
    const int start = s_pref[k], len = s_hist[k];
    float4 a0 = {0.f, 0.f, 0.f, 0.f}, a1 = {0.f, 0.f, 0.f, 0.f};
    int i = 0;
    for (; i + 4 <= len; i += 4) {            // unroll x4: 8 loads in flight
        const int i0 = s_idx[start + i + 0];
        const int i1 = s_idx[start + i + 1];
        const int i2 = s_idx[start + i + 2];
        const int i3 = s_idx[start + i + 3];
        const float4* r0 = (const float4*)(feat + (base + i0) * D + q * 8);
        const float4* r1 = (const float4*)(feat + (base + i1) * D + q * 8);
        const float4* r2 = (const float4*)(feat + (base + i2) * D + q * 8);
        const float4* r3 = (const float4*)(feat + (base + i3) * D + q * 8);
        const float4 x0 = r0[0], y0 = r0[1];
        const float4 x1 = r1[0], y1 = r1[1];
        const float4 x2 = r2[0], y2 = r2[1];
        const float4 x3 = r3[0], y3 = r3[1];
        a0.x += (x0.x + x1.x) + (x2.x + x3.x);
        a0.y += (x0.y + x1.y) + (x2.y + x3.y);
        a0.z += (x0.z + x1.z) + (x2.z + x3.z);
        a0.w += (x0.w + x1.w) + (x2.w + x3.w);
        a1.x += (y0.x + y1.x) + (y2.x + y3.x);
        a1.y += (y0.y + y1.y) + (y2.y + y3.y);
        a1.z += (y0.z + y1.z) + (y2.z + y3.z);
        a1.w += (y0.w + y1.w) + (y2.w + y3.w);
    }
    for (; i < len; ++i) {
        const int i0 = s_idx[start + i];
        const float4* r0 = (const float4*)(feat + (base + i0) * D + q * 8);
        const float4 x0 = r0[0], y0 = r0[1];
        a0.x += x0.x; a0.y += x0.y; a0.z += x0.z; a0.w += x0.w;
        a1.x += y0.x; a1.y += y0.y; a1.z += y0.z; a1.w += y0.w;
    }
    float* outp = part1 + (long long)blockIdx.x * P1;
    ((float4*)outp)[tid * 2 + 0] = a0;        // cell k*32 + q*8 == tid*8
    ((float4*)outp)[tid * 2 + 1] = a1;
    if (tid < K) outp[K * D + tid] = (float)s_hist[tid];
}

// ------- reduce: chunk-partials -> fire-and-forget atomics into sums -------
__global__ __launch_bounds__(256) void reduce1_kernel(
    const float* __restrict__ part1, float* __restrict__ sums,
    int chsz, int nblk1)
{
    const int e = blockIdx.x * 256 + threadIdx.x;
    if (e >= P1) return;
    const int y = blockIdx.y;
    const int b0 = y * chsz;
    int b1 = b0 + chsz; if (b1 > nblk1) b1 = nblk1;
    float s = 0.f;
    for (int b = b0; b < b1; b++) s += part1[(long long)b * P1 + e];
    atomicAdd(&sums[e], s);                   // non-returning, 64 contenders
}

// ---------------- pass 2: means-from-sums prologue + hinge + block0 epi ----
__global__ __launch_bounds__(256, 4) void pass2_kernel(
    const float* __restrict__ feat, const int* __restrict__ lab,
    const float* __restrict__ sums,
    float* __restrict__ hpart, float* __restrict__ ir, int N)
{
    __shared__ float s_m[K * MPAD];   // padded means, 10 KB
    __shared__ float s_ic[K];
    __shared__ float s_red[256];
    const int tid = threadIdx.x;

    for (int e = tid; e < K * D; e += 256) {          // means = sums / cnt
        const float c = sums[K * D + (e >> 5)];       // broadcast line, L2-hot
        s_m[(e >> 5) * MPAD + (e & 31)] = sums[e] / fmaxf(c, 1.0f);
    }
    if (tid < K) s_ic[tid] = 1.0f / fmaxf(sums[K * D + tid], 1.0f);
    __syncthreads();

    float racc = 0.f;
    const long long stride = (long long)NBLK2 * 256;
    for (long long p = (long long)blockIdx.x * 256 + tid; p < N; p += stride) {
        const int l = lab[p];
        const float4* frow = (const float4*)(feat + p * D);
        float4 fv[8];
        #pragma unroll
        for (int j = 0; j < 8; j++) fv[j] = frow[j];   // 8 loads in flight
        const float* mrow = s_m + l * MPAD;
        float d2 = 0.f;
        #pragma unroll
        for (int j = 0; j < 8; j++) {
            const float4 mv = *(const float4*)(mrow + j * 4);
            const float dx = fv[j].x - mv.x + EPS_F;
            const float dy = fv[j].y - mv.y + EPS_F;
            const float dz = fv[j].z - mv.z + EPS_F;
            const float dw = fv[j].w - mv.w + EPS_F;
            d2 += dx * dx + dy * dy + dz * dz + dw * dw;
        }
        const float h = fmaxf(sqrtf(d2) - 1.5f, 0.f);  // INTRA_MARGIN_USED
        racc += h * h * s_ic[l];
    }
    s_red[tid] = racc;
    __syncthreads();
    for (int st = 128; st; st >>= 1) { if (tid < st) s_red[tid] += s_red[tid + st]; __syncthreads(); }
    if (tid == 0) hpart[blockIdx.x] = s_red[0];

    if (blockIdx.x != 0) return;
    // ---- block 0 epilogue: inter + reg from s_m (overlaps other blocks) ----
    __syncthreads();
    float mj[32];
    const int j = tid & 63;
    #pragma unroll
    for (int d = 0; d < 32; d++) mj[d] = s_m[j * MPAD + d];
    float isum = 0.f;
    const int igrp = tid >> 6;        // 0..3, 16 i's each; i wave-uniform
    for (int ii = 0; ii < 16; ii++) {
        const int i = igrp * 16 + ii;
        const float4* srow = (const float4*)(s_m + i * MPAD);
        float d2 = 0.f;
        #pragma unroll
        for (int q = 0; q < 8; q++) {
            const float4 mv = srow[q];
            const float b0 = mv.x - mj[q * 4 + 0] + EPS_F;
            const float b1 = mv.y - mj[q * 4 + 1] + EPS_F;
            const float b2 = mv.z - mj[q * 4 + 2] + EPS_F;
            const float b3 = mv.w - mj[q * 4 + 3] + EPS_F;
            d2 += b0 * b0 + b1 * b1 + b2 * b2 + b3 * b3;
        }
        if (i != j) {
            const float h = fmaxf(1.0f - sqrtf(d2), 0.f);  // 2*margin - pd
            isum += h * h;
        }
    }
    s_red[tid] = isum;
    __syncthreads();
    for (int st = 128; st; st >>= 1) { if (tid < st) s_red[tid] += s_red[tid + st]; __syncthreads(); }
    if (tid == 0) ir[0] = s_red[0] * (1.0f / ((K - 1) * K));
    __syncthreads();

    float r = 0.f;
    if (tid < 64) {
        float d2 = 0.f;
        #pragma unroll
        for (int d = 0; d < 32; d++) { const float t = mj[d] + EPS_F; d2 += t * t; }
        r = sqrtf(d2);
    }
    s_red[tid] = r;
    __syncthreads();
    for (int st = 128; st; st >>= 1) { if (tid < st) s_red[tid] += s_red[tid + st]; __syncthreads(); }
    if (tid == 0) ir[1] = s_red[0] * (1.0f / K);
}

// ---------------- final: hpart sum + combine --------------------------------
__global__ __launch_bounds__(256) void final_kernel(
    const float* __restrict__ hpart, const float* __restrict__ ir,
    float* __restrict__ out)
{
    __shared__ float s_red[256];
    const int tid = threadIdx.x;
    float hs = 0.f;
    for (int b = tid; b < NBLK2; b += 256) hs += hpart[b];
    s_red[tid] = hs;
    __syncthreads();
    for (int st = 128; st; st >>= 1) { if (tid < st) s_red[tid] += s_red[tid + st]; __syncthreads(); }
    if (tid == 0) out[0] = s_red[0] * (1.0f / K) + ir[0] + 0.001f * ir[1];
}

extern "C" void kernel_launch(void* const* d_in, const int* in_sizes, int n_in,
                              void* d_out, int out_size, void* d_ws, size_t ws_size,
                              hipStream_t stream)
{
    const float* feat = (const float*)d_in[0];
    const int*   lab  = (const int*)d_in[1];
    const int N = in_sizes[1];            // 1e6; D=32, K=64 fixed by reference

    float* ws = (float*)d_ws;

    const int nblk1 = (N + NPTS - 1) / NPTS;         // 977
    const int chsz  = (nblk1 + NCH - 1) / NCH;       // 16

    float* sums  = ws;                               // P1 (sums + counts)
    float* ir    = sums + P1;                        // 2 (+pad 2)
    float* hpart = ir + 4;                           // NBLK2
    float* part1 = hpart + NBLK2;                    // nblk1*P1

    pass1_kernel<<<nblk1, 256, 0, stream>>>(feat, lab, part1, sums, N);
    reduce1_kernel<<<dim3((P1 + 255) / 256, NCH), 256, 0, stream>>>(part1, sums, chsz, nblk1);
    pass2_kernel<<<NBLK2, 256, 0, stream>>>(feat, lab, sums, hpart, ir, N);
    final_kernel<<<1, 256, 0, stream>>>(hpart, ir, (float*)d_out);
}